// Round 16
// baseline (1274.843 us; speedup 1.0000x reference)
//
#include <hip/hip_runtime.h>
#include <hip/hip_cooperative_groups.h>
#include <cstddef>

#define DINL static __device__ __forceinline__

namespace cg = cooperative_groups;

// collision-proof custom vector types (HIP headers own names like short8/float4)
typedef __attribute__((ext_vector_type(4))) float f4v;
typedef __attribute__((ext_vector_type(8))) short bh8;   // 8 bf16 bit patterns (4 VGPRs)
typedef __attribute__((ext_vector_type(4))) unsigned short us4;  // 4 bf16 (8 B)

// rot90 applied r times (counter-clockwise, numpy convention): rotated_r[i][j] = w[si][sj]
DINL void rot_src(int r, int K, int i, int j, int& si, int& sj) {
  switch (r & 3) {
    case 0:  si = i;       sj = j;       break;
    case 1:  si = j;       sj = K-1-i;   break;
    case 2:  si = K-1-i;   sj = K-1-j;   break;
    default: si = K-1-j;   sj = i;       break;
  }
}

DINL float sigmoidf(float s) { return 1.f / (1.f + __expf(-s)); }

DINL unsigned short f2bf(float f) {
  unsigned u = __builtin_bit_cast(unsigned, f);
  u += 0x7fffu + ((u >> 16) & 1u);
  return (unsigned short)(u >> 16);
}
DINL float bf2f(unsigned short h) {
  unsigned u = ((unsigned)h) << 16;
  return __builtin_bit_cast(float, u);
}

struct MP {
  const float* x;  const float* w1; const float* b1; const float* aw1;
  const float* W[6]; const float* BI[6]; const float* AW[6];
  const float* Gm[6]; const float* BE[6];
  float* out;
  unsigned short* YR; unsigned short* XN; unsigned short* AMAP; unsigned short* WROT;
  float* ATT; float* PART;
};

// ---------------- parallel BN finalize from bucketed partials (in LDS) ----------------
DINL void bn_finalize_par(const float* __restrict__ partl,
                          const float* __restrict__ gamma, const float* __restrict__ beta,
                          float* st, float* l1, float* l2, int npix, int tid) {
  {
    int c = tid & 31, grp = tid >> 5;
    float s1 = 0.f, s2 = 0.f;
    #pragma unroll
    for (int k = 0; k < 8; ++k) {
      int bk = grp * 8 + k;
      s1 += partl[bk * 128 + c];
      s2 += partl[bk * 128 + 64 + c];
    }
    l1[tid] = s1; l2[tid] = s2;
  }
  __syncthreads();
  if (tid < 32) {
    float a = 0.f, q = 0.f;
    #pragma unroll
    for (int k = 0; k < 8; ++k) { a += l1[k * 32 + tid]; q += l2[k * 32 + tid]; }
    float N = 4.f * (float)npix;
    float m = a / N;
    float v = q / N - m * m;
    float inv = rsqrtf(v + 2e-5f);
    float sc = gamma[tid] * inv;
    st[tid] = sc;
    st[32 + tid] = beta[tid] - m * sc;
  }
  __syncthreads();
}

// ---------------- MFMA attentive GG conv stage (vb loop) ----------------
// xn [b][p][128] bf16 (c' = g*32+ci), att fp32, weights coalesced bh8
// wrot[r][tap][ks][mi][lane][j8]. Split-K staging (64ch halves). Out y bf16 c'=r*O+o.
template<int H, int OM, int O, int OSTR, bool BNS>
DINL void dev_conv(const unsigned short* __restrict__ xn, const float* __restrict__ att,
                   const unsigned short* __restrict__ wl, const float* __restrict__ bias,
                   unsigned short* __restrict__ y, float* __restrict__ partl,
                   float* sm, int tid, int bid, int G) {
  constexpr int HO = H - 2, HW = H * H;
  constexpr int TR = 8, TC = 16, WR = TR + 2, WC = TC + 2, CGH = 68;
  constexpr int NRT = (HO + TR - 1) / TR, NCT = (HO + TC - 1) / TC;
  constexpr int VG = 8 * (NRT * NCT) * 16;
  unsigned short* xa = (unsigned short*)sm;        // 12240 ushorts max (H=46)
  float* bnred = sm + 6120;                        // 128 floats

  int lane = tid & 63;
  int wv = tid >> 6;
  int n = lane & 15, quad = lane >> 4;

  for (int vb = bid; vb < VG; vb += G) {
    int id = vb;
    int slot = id & 7; int k = id >> 3;
    int tile = k % (NRT * NCT); k /= (NRT * NCT);
    int r = k & 3; int bhi = k >> 2;
    int b = bhi * 8 + slot;
    int rt = tile / NCT, ct = tile % NCT;
    int row0 = rt * TR, c0 = ct * TC;

    const unsigned short* xb = xn + (size_t)b * HW * 128;
    const float* ab = att + (size_t)(b * 4 + r) * HW;

    f4v acc[OM][2];
    #pragma unroll
    for (int mi = 0; mi < OM; ++mi)
      #pragma unroll
      for (int ri = 0; ri < 2; ++ri) {
        acc[mi][ri][0] = 0.f; acc[mi][ri][1] = 0.f;
        acc[mi][ri][2] = 0.f; acc[mi][ri][3] = 0.f;
      }

    const bh8* wa = (const bh8*)wl + (size_t)r * 9 * 4 * OM * 64 + lane;

    for (int half = 0; half < 2; ++half) {
      if (half) __syncthreads();
      for (int u = tid; u < WR * WC * 8; u += 256) {
        int ch = u & 7; int pix = u >> 3;
        int wr = pix / WC, wc = pix % WC;
        int row = row0 + wr; if (row > H - 1) row = H - 1;
        int col = c0 + wc;  if (col > H - 1) col = H - 1;
        int p = row * H + col;
        const unsigned short* xp = xb + (size_t)p * 128 + half * 64 + ch * 8;
        float av = ab[p];
        bh8 xv = *(const bh8*)xp;
        bh8 v;
        #pragma unroll
        for (int j2 = 0; j2 < 8; ++j2)
          v[j2] = (short)f2bf(bf2f((unsigned short)xv[j2]) * av);
        *(bh8*)&xa[pix * CGH + ch * 8] = v;
      }
      __syncthreads();

      #pragma unroll
      for (int tap = 0; tap < 9; ++tap) {
        int ky = tap / 3, kx = tap % 3;
        int pb0 = ((2 * wv + ky) * WC + n + kx) * CGH;
        int pb1 = pb0 + WC * CGH;
        #pragma unroll
        for (int kl = 0; kl < 2; ++kl) {
          int ks = half * 2 + kl;
          bh8 b0 = *(const bh8*)&xa[pb0 + kl * 32 + quad * 8];
          bh8 b1 = *(const bh8*)&xa[pb1 + kl * 32 + quad * 8];
          bh8 a0 = wa[(size_t)((tap * 4 + ks) * OM + 0) * 64];
          acc[0][0] = __builtin_amdgcn_mfma_f32_16x16x32_bf16(a0, b0, acc[0][0], 0, 0, 0);
          acc[0][1] = __builtin_amdgcn_mfma_f32_16x16x32_bf16(a0, b1, acc[0][1], 0, 0, 0);
          if constexpr (OM == 2) {
            bh8 a1 = wa[(size_t)((tap * 4 + ks) * OM + 1) * 64];
            acc[1][0] = __builtin_amdgcn_mfma_f32_16x16x32_bf16(a1, b0, acc[1][0], 0, 0, 0);
            acc[1][1] = __builtin_amdgcn_mfma_f32_16x16x32_bf16(a1, b1, acc[1][1], 0, 0, 0);
          }
        }
      }
    }

    // epilogue: C/D col=lane&15 (spatial), row=quad*4+reg (o); c' = r*O + o
    float sv[OM * 4], qv[OM * 4];
    #pragma unroll
    for (int e = 0; e < OM * 4; ++e) { sv[e] = 0.f; qv[e] = 0.f; }
    #pragma unroll
    for (int mi = 0; mi < OM; ++mi)
      #pragma unroll
      for (int ri = 0; ri < 2; ++ri) {
        int prow = row0 + 2 * wv + ri;
        int col = c0 + n;
        if (prow < HO && col < HO) {
          unsigned short* yp = y + ((size_t)b * HO * HO + prow * HO + col) * OSTR;
          int o0 = mi * 16 + quad * 4;
          f4v v = acc[mi][ri];
          if constexpr (O == 32) {
            us4 w4;
            #pragma unroll
            for (int reg = 0; reg < 4; ++reg) {
              float val = v[reg] + bias[o0 + reg];
              w4[reg] = f2bf(val);
              if constexpr (BNS) { sv[mi * 4 + reg] += val; qv[mi * 4 + reg] += val * val; }
            }
            *(us4*)(yp + r * 32 + o0) = w4;
          } else {
            #pragma unroll
            for (int reg = 0; reg < 4; ++reg) {
              int o = o0 + reg;
              if (o < O) yp[r * O + o] = f2bf(v[reg] + bias[o]);
            }
          }
        }
      }

    if constexpr (BNS) {
      #pragma unroll
      for (int e = 0; e < OM * 4; ++e) {
        #pragma unroll
        for (int off = 1; off < 16; off <<= 1) {
          sv[e] += __shfl_xor(sv[e], off);
          qv[e] += __shfl_xor(qv[e], off);
        }
      }
      if (tid < 128) bnred[tid] = 0.f;
      __syncthreads();
      if (n == 0) {
        #pragma unroll
        for (int e = 0; e < OM * 4; ++e) {
          int o = (e >> 2) * 16 + quad * 4 + (e & 3);
          atomicAdd(&bnred[o], sv[e]);
          atomicAdd(&bnred[64 + o], qv[e]);
        }
      }
      __syncthreads();
      if (tid < 128)
        atomicAdd(&partl[(vb & 63) * 128 + tid], bnred[tid]);
    }
    __syncthreads();   // protect xa/bnred before next vb iteration
  }
}

// ---------------- BN+ReLU+mean/max stage (no pool) ----------------
DINL void dev_mm(const unsigned short* __restrict__ yr, const float* __restrict__ partl,
                 const float* __restrict__ gamma, const float* __restrict__ beta,
                 unsigned short* __restrict__ xn, unsigned short* __restrict__ amap,
                 int npixb, float* sm, int tid, int bid, int G) {
  float* st = sm;
  bn_finalize_par(partl, gamma, beta, st, sm + 64, sm + 320, 32 * npixb, tid);
  int tot = 32 * npixb;
  for (int idx = bid * 256 + tid; idx < tot; idx += G * 256) {
    const unsigned short* yp = yr + (size_t)idx * 128;
    unsigned short* xp = xn + (size_t)idx * 128;
    float smv[4] = {0.f, 0.f, 0.f, 0.f};
    float mx[4] = {-1e30f, -1e30f, -1e30f, -1e30f};
    #pragma unroll 4
    for (int oo = 0; oo < 16; ++oo) {
      int g = oo >> 2, ob = (oo & 3) * 8;
      bh8 raw = *(const bh8*)(yp + oo * 8);
      bh8 w;
      #pragma unroll
      for (int e = 0; e < 8; ++e) {
        float v = fmaxf(fmaf(bf2f((unsigned short)raw[e]), st[ob + e], st[32 + ob + e]), 0.f);
        w[e] = (short)f2bf(v);
        smv[g] += v;
        mx[g] = fmaxf(mx[g], v);
      }
      *(bh8*)(xp + oo * 8) = w;
    }
    bh8 am;
    #pragma unroll
    for (int g = 0; g < 4; ++g) {
      am[g] = (short)f2bf(smv[g] * (1.f / 32.f));
      am[4 + g] = (short)f2bf(mx[g]);
    }
    *(bh8*)(amap + (size_t)idx * 8) = am;
  }
}

// ---------------- L2 variant: BN+ReLU at 44x44 then 2x2 maxpool -> 22x22 ----------------
DINL void dev_mm_pool(const unsigned short* __restrict__ yr, const float* __restrict__ partl,
                      const float* __restrict__ gamma, const float* __restrict__ beta,
                      unsigned short* __restrict__ xn, unsigned short* __restrict__ amap,
                      float* sm, int tid, int bid, int G) {
  const int HI = 44, HOq = 22, HWO = HOq * HOq;
  float* st = sm;
  bn_finalize_par(partl, gamma, beta, st, sm + 64, sm + 320, 32 * HI * HI, tid);
  int tot = 32 * HWO;
  for (int idx = bid * 256 + tid; idx < tot; idx += G * 256) {
    int p22 = idx % HWO; int b = idx / HWO;
    int y0 = (p22 / HOq) * 2, x0 = (p22 % HOq) * 2;
    const unsigned short* p00 = yr + ((size_t)b * HI * HI + y0 * HI + x0) * 128;
    unsigned short* xp = xn + (size_t)idx * 128;
    float smv[4] = {0.f, 0.f, 0.f, 0.f};
    float mx[4] = {-1e30f, -1e30f, -1e30f, -1e30f};
    #pragma unroll 2
    for (int oo = 0; oo < 16; ++oo) {
      int g = oo >> 2, ob = (oo & 3) * 8;
      bh8 r0 = *(const bh8*)(p00 + oo * 8);
      bh8 r1 = *(const bh8*)(p00 + 128 + oo * 8);
      bh8 r2 = *(const bh8*)(p00 + (size_t)HI * 128 + oo * 8);
      bh8 r3 = *(const bh8*)(p00 + (size_t)(HI + 1) * 128 + oo * 8);
      bh8 w;
      #pragma unroll
      for (int e = 0; e < 8; ++e) {
        float sc = st[ob + e], sh = st[32 + ob + e];
        float a0 = fmaxf(fmaf(bf2f((unsigned short)r0[e]), sc, sh), 0.f);
        float a1 = fmaxf(fmaf(bf2f((unsigned short)r1[e]), sc, sh), 0.f);
        float a2 = fmaxf(fmaf(bf2f((unsigned short)r2[e]), sc, sh), 0.f);
        float a3 = fmaxf(fmaf(bf2f((unsigned short)r3[e]), sc, sh), 0.f);
        float val = fmaxf(fmaxf(a0, a1), fmaxf(a2, a3));
        w[e] = (short)f2bf(val);
        smv[g] += val; mx[g] = fmaxf(mx[g], val);
      }
      *(bh8*)(xp + oo * 8) = w;
    }
    bh8 am;
    #pragma unroll
    for (int g = 0; g < 4; ++g) {
      am[g] = (short)f2bf(smv[g] * (1.f / 32.f));
      am[4 + g] = (short)f2bf(mx[g]);
    }
    *(bh8*)(amap + (size_t)idx * 8) = am;
  }
}

// ---------------- attention GG conv stage (LDS-staged rotated weights) ----------------
DINL void dev_att(const unsigned short* __restrict__ amap, const float* __restrict__ aw,
                  float* __restrict__ att, int h, float* sm, int tid, int bid, int G) {
  float* wsa = sm;          // [4][4][49] = 784
  float* wsx = sm + 784;
  for (int i = tid; i < 784; i += 256) {
    int r = i / 196; int rem = i % 196;
    int g = rem / 49; int t = rem % 49;
    int ky = t / 7, kx = t % 7;
    int si, sj; rot_src(r, 7, ky, kx, si, sj);
    int gs = (g - r) & 3;
    wsa[i] = aw[gs * 49 + si * 7 + sj];
    wsx[i] = aw[(4 + gs) * 49 + si * 7 + sj];
  }
  __syncthreads();
  int hw = h * h;
  int tot = 32 * 4 * hw;
  for (int idx = bid * 256 + tid; idx < tot; idx += G * 256) {
    int p = idx % hw; int t = idx / hw;
    int r = t & 3; int b = t >> 2;
    int yh = p / h, xw = p % h;
    float s = 0.f;
    for (int ky = 0; ky < 7; ++ky) {
      int y = yh + ky - 3;
      if ((unsigned)y >= (unsigned)h) continue;
      for (int kx = 0; kx < 7; ++kx) {
        int xx = xw + kx - 3;
        if ((unsigned)xx >= (unsigned)h) continue;
        int tp = ky * 7 + kx;
        bh8 av = *(const bh8*)(amap + ((size_t)b * hw + y * h + xx) * 8);
        #pragma unroll
        for (int g = 0; g < 4; ++g)
          s += bf2f((unsigned short)av[g]) * wsa[(r * 4 + g) * 49 + tp]
             + bf2f((unsigned short)av[4 + g]) * wsx[(r * 4 + g) * 49 + tp];
      }
    }
    att[((size_t)(b * 4 + r)) * hw + p] = sigmoidf(s);
  }
}

// ---------------- the mega kernel ----------------
__global__ void __launch_bounds__(256, 2) k_mega(MP p) {
  cg::grid_group grid = cg::this_grid();
  __shared__ __align__(16) float sm[6400];   // 25.6 KB arena, re-used per stage
  const int tid = threadIdx.x;
  const int bid = blockIdx.x;
  const int G = gridDim.x;
  const int NT = G * 256;
  const int gtid = bid * 256 + tid;

  float* PL[6];
  #pragma unroll
  for (int i = 0; i < 6; ++i) PL[i] = p.PART + i * 8192;

  // ---- S0: zero PART + weight prep ----
  for (int i = gtid; i < 6 * 8192; i += NT) p.PART[i] = 0.f;
  for (int idx = gtid; idx < 811008; idx += NT) {
    const float* w; int OM, O, base;
    if (idx < 737280) {
      int L = idx / 147456; base = L * 147456; OM = 2; O = 32;
      w = p.W[L];
    } else { base = 737280; OM = 1; O = 10; w = p.W[5]; }
    int local = idx - base;
    int j = local & 7; int t = local >> 3;
    int lanei = t & 63; t >>= 6;
    int mi = t % OM; t /= OM;
    int ks = t & 3; t >>= 2;
    int tap = t % 9; int r = t / 9;
    int n = lanei & 15, q = lanei >> 4;
    int o = mi * 16 + n;
    int ci = q * 8 + j;
    int gs = (ks - r) & 3;
    int ky = tap / 3, kx = tap % 3;
    int si, sj; rot_src(r, 3, ky, kx, si, sj);
    float val = (o < O) ? w[((o * 32 + ci) * 4 + gs) * 9 + si * 3 + sj] : 0.f;
    p.WROT[idx] = f2bf(val);
  }
  grid.sync();

  // ---- S1: L1 attention (lift) ----
  {
    float* wsum = sm;  // [4][49]
    for (int i = tid; i < 196; i += 256) {
      int r = i / 49; int t = i % 49;
      int ky = t / 7, kx = t % 7;
      int si, sj; rot_src(r, 7, ky, kx, si, sj);
      wsum[i] = p.aw1[si * 7 + sj] + p.aw1[49 + si * 7 + sj];
    }
    __syncthreads();
    const int H = 48, HW = H * H;
    for (int idx = gtid; idx < 32 * 4 * HW; idx += NT) {
      int xw = idx % H; int t = idx / H;
      int yh = t % H;  t /= H;
      int r  = t & 3;  int b = t >> 2;
      const float* xb = p.x + b * HW;
      float s = 0.f;
      for (int ky = 0; ky < 7; ++ky) {
        int y = yh + ky - 3;
        if ((unsigned)y >= (unsigned)H) continue;
        for (int kx = 0; kx < 7; ++kx) {
          int xx = xw + kx - 3;
          if ((unsigned)xx >= (unsigned)H) continue;
          s += xb[y * H + xx] * wsum[r * 49 + ky * 7 + kx];
        }
      }
      p.ATT[idx] = sigmoidf(s);
    }
  }
  grid.sync();

  // ---- S2: L1 lifting conv + BN stats ----
  {
    const int HO = 46;
    float* xs = sm;          // 144
    float* as_ = sm + 144;   // 4*144 = 576
    float* wsm = sm + 720;   // 288
    float* bs = sm + 1008;   // 32
    float* bnred = sm + 1040; // 64
    for (int vb = bid; vb < 32 * 46; vb += G) {
      int yo = vb % HO; int b = vb / HO;
      for (int i = tid; i < 144; i += 256)
        xs[i] = p.x[b * 2304 + (yo + i / 48) * 48 + (i % 48)];
      for (int i = tid; i < 576; i += 256) {
        int r = i / 144; int rem = i % 144;
        as_[r * 144 + rem] = p.ATT[(b * 4 + r) * 2304 + (yo + rem / 48) * 48 + (rem % 48)];
      }
      for (int i = tid; i < 288; i += 256) wsm[i] = p.w1[i];
      if (tid < 32) bs[tid] = p.b1[tid];
      if (tid < 64) bnred[tid] = 0.f;
      __syncthreads();

      int o = tid & 31;
      int cl = tid >> 5;
      float wreg[9];
      #pragma unroll
      for (int i = 0; i < 9; ++i) wreg[i] = wsm[o * 9 + i];
      float bv = bs[o];
      float sacc = 0.f, qacc = 0.f;
      for (int c8 = 0; c8 < 6; ++c8) {
        int col = c8 * 8 + cl;
        if (col < HO) {
          float xv[9];
          #pragma unroll
          for (int ky = 0; ky < 3; ++ky)
            #pragma unroll
            for (int kx = 0; kx < 3; ++kx)
              xv[ky * 3 + kx] = xs[ky * 48 + col + kx];
          unsigned short* yp = p.YR + ((size_t)b * 2116 + yo * HO + col) * 128 + o;
          #pragma unroll
          for (int r = 0; r < 4; ++r) {
            float acc = bv;
            #pragma unroll
            for (int ky = 0; ky < 3; ++ky)
              #pragma unroll
              for (int kx = 0; kx < 3; ++kx) {
                int si, sj; rot_src(r, 3, ky, kx, si, sj);
                acc = fmaf(as_[r * 144 + ky * 48 + col + kx] * xv[ky * 3 + kx],
                           wreg[si * 3 + sj], acc);
              }
            yp[r * 32] = f2bf(acc);
            sacc += acc; qacc += acc * acc;
          }
        }
      }
      atomicAdd(&bnred[o], sacc);
      atomicAdd(&bnred[32 + o], qacc);
      __syncthreads();
      if (tid < 64) {
        int bucket = vb & 63;
        int c = tid & 31;
        int off = (tid < 32) ? c : (64 + c);
        atomicAdd(&PL[0][bucket * 128 + off], bnred[tid]);
      }
      __syncthreads();
    }
  }
  grid.sync();

  // ---- S3: L1 meanmax+BN ----
  dev_mm(p.YR, PL[0], p.Gm[0], p.BE[0], p.XN, p.AMAP, 2116, sm, tid, bid, G);
  grid.sync();
  // ---- S4: L1 att (h=46) ----
  dev_att(p.AMAP, p.AW[0], p.ATT, 46, sm, tid, bid, G);
  grid.sync();

  // ---- L2 ----
  dev_conv<46, 2, 32, 128, true>(p.XN, p.ATT, p.WROT + 0 * 147456, p.BI[0], p.YR, PL[1], sm, tid, bid, G);
  grid.sync();
  dev_mm_pool(p.YR, PL[1], p.Gm[1], p.BE[1], p.XN, p.AMAP, sm, tid, bid, G);
  grid.sync();
  dev_att(p.AMAP, p.AW[1], p.ATT, 22, sm, tid, bid, G);
  grid.sync();

  // ---- L3 ----
  dev_conv<22, 2, 32, 128, true>(p.XN, p.ATT, p.WROT + 1 * 147456, p.BI[1], p.YR, PL[2], sm, tid, bid, G);
  grid.sync();
  dev_mm(p.YR, PL[2], p.Gm[2], p.BE[2], p.XN, p.AMAP, 400, sm, tid, bid, G);
  grid.sync();
  dev_att(p.AMAP, p.AW[2], p.ATT, 20, sm, tid, bid, G);
  grid.sync();

  // ---- L4 ----
  dev_conv<20, 2, 32, 128, true>(p.XN, p.ATT, p.WROT + 2 * 147456, p.BI[2], p.YR, PL[3], sm, tid, bid, G);
  grid.sync();
  dev_mm(p.YR, PL[3], p.Gm[3], p.BE[3], p.XN, p.AMAP, 324, sm, tid, bid, G);
  grid.sync();
  dev_att(p.AMAP, p.AW[3], p.ATT, 18, sm, tid, bid, G);
  grid.sync();

  // ---- L5 ----
  dev_conv<18, 2, 32, 128, true>(p.XN, p.ATT, p.WROT + 3 * 147456, p.BI[3], p.YR, PL[4], sm, tid, bid, G);
  grid.sync();
  dev_mm(p.YR, PL[4], p.Gm[4], p.BE[4], p.XN, p.AMAP, 256, sm, tid, bid, G);
  grid.sync();
  dev_att(p.AMAP, p.AW[4], p.ATT, 16, sm, tid, bid, G);
  grid.sync();

  // ---- L6 ----
  dev_conv<16, 2, 32, 128, true>(p.XN, p.ATT, p.WROT + 4 * 147456, p.BI[4], p.YR, PL[5], sm, tid, bid, G);
  grid.sync();
  dev_mm(p.YR, PL[5], p.Gm[5], p.BE[5], p.XN, p.AMAP, 196, sm, tid, bid, G);
  grid.sync();
  dev_att(p.AMAP, p.AW[5], p.ATT, 14, sm, tid, bid, G);
  grid.sync();

  // ---- L7 (O=10, no BN) ----
  dev_conv<14, 1, 10, 40, false>(p.XN, p.ATT, p.WROT + 737280, p.BI[5], p.YR, nullptr, sm, tid, bid, G);
  grid.sync();

  // ---- final: rotation max + spatial mean ----
  for (int idx = gtid; idx < 320; idx += NT) {
    int o = idx % 10; int b = idx / 10;
    const unsigned short* q0 = p.YR + (size_t)b * 144 * 40;
    float s = 0.f;
    for (int sp = 0; sp < 144; ++sp) {
      const unsigned short* q = q0 + sp * 40 + o;
      float m = fmaxf(fmaxf(bf2f(q[0]), bf2f(q[10])), fmaxf(bf2f(q[20]), bf2f(q[30])));
      s += m;
    }
    p.out[idx] = s * (1.f / 144.f);
  }
}

// ---------------- host ----------------

extern "C" void kernel_launch(void* const* d_in, const int* in_sizes, int n_in,
                              void* d_out, int out_size, void* d_ws, size_t ws_size,
                              hipStream_t stream) {
  (void)in_sizes; (void)n_in; (void)out_size; (void)ws_size;
  MP mp;
  mp.x   = (const float*)d_in[0];
  mp.w1  = (const float*)d_in[1];
  mp.b1  = (const float*)d_in[2];
  mp.aw1 = (const float*)d_in[3];
  for (int i = 0; i < 6; ++i) {
    mp.W[i]  = (const float*)d_in[4 + 3 * i];
    mp.BI[i] = (const float*)d_in[5 + 3 * i];
    mp.AW[i] = (const float*)d_in[6 + 3 * i];
  }
  for (int i = 0; i < 6; ++i) {
    mp.Gm[i] = (const float*)d_in[22 + 2 * i];
    mp.BE[i] = (const float*)d_in[23 + 2 * i];
  }
  mp.out = (float*)d_out;

  // workspace (floats): ~38.8 MB
  float* ws = (float*)d_ws;
  mp.YR   = (unsigned short*)ws;                  // raw conv out bf16
  mp.XN   = (unsigned short*)(ws + 4333568);      // normalized xn bf16
  mp.AMAP = (unsigned short*)(ws + 8667136);      // amap bf16
  mp.ATT  = ws + 8937984;                         // fp32 attention
  mp.WROT = (unsigned short*)(ws + 9232896);      // prepped weights
  mp.PART = ws + 9638400;                         // 6 x 8192 BN buckets

  int nb = 0;
  hipError_t err = hipOccupancyMaxActiveBlocksPerMultiprocessor(&nb, k_mega, 256, 0);
  if (err != hipSuccess || nb < 1) nb = 1;
  if (nb > 4) nb = 4;
  int G = 256 * nb;
  if (G > 2304) G = 2304;

  void* args[] = { &mp };
  hipLaunchCooperativeKernel(k_mega, dim3(G), dim3(256), args, 0, stream);
}

// Round 17
// 491.119 us; speedup vs baseline: 2.5958x; 2.5958x over previous
//
#include <hip/hip_runtime.h>
#include <cstddef>

#define DINL static __device__ __forceinline__

// collision-proof custom vector types (HIP headers own names like short8/float4)
typedef __attribute__((ext_vector_type(4))) float f4v;
typedef __attribute__((ext_vector_type(8))) short bh8;   // 8 bf16 bit patterns (4 VGPRs)
typedef __attribute__((ext_vector_type(4))) unsigned short us4;  // 4 bf16 (8 B)

// rot90 applied r times (counter-clockwise, numpy convention): rotated_r[i][j] = w[si][sj]
DINL void rot_src(int r, int K, int i, int j, int& si, int& sj) {
  switch (r & 3) {
    case 0:  si = i;       sj = j;       break;
    case 1:  si = j;       sj = K-1-i;   break;
    case 2:  si = K-1-i;   sj = K-1-j;   break;
    default: si = K-1-j;   sj = i;       break;
  }
}

DINL float sigmoidf(float s) { return 1.f / (1.f + __expf(-s)); }

// float -> bf16 bits, round-to-nearest-even
DINL unsigned short f2bf(float f) {
  unsigned u = __builtin_bit_cast(unsigned, f);
  u += 0x7fffu + ((u >> 16) & 1u);
  return (unsigned short)(u >> 16);
}
DINL float bf2f(unsigned short h) {
  unsigned u = ((unsigned)h) << 16;
  return __builtin_bit_cast(float, u);
}

// ---------------- weight prep ----------------
// Activation channel layout: c' = g*32 + ci. A-fragment coalesced layout:
// bh8 wrot[r][tap][ks][mi][lane(=16q+n)][j8]; cg = ks*32 + q*8 + j.
__global__ void k_prep_w(const float* __restrict__ w2, const float* __restrict__ w3,
                         const float* __restrict__ w4, const float* __restrict__ w5,
                         const float* __restrict__ w6, const float* __restrict__ w7,
                         unsigned short* __restrict__ wrot) {
  int idx = blockIdx.x * 256 + threadIdx.x;
  if (idx >= 811008) return;
  const float* w; int OM, O, base;
  if (idx < 737280) {
    int L = idx / 147456; base = L * 147456; OM = 2; O = 32;
    w = (L == 0) ? w2 : (L == 1) ? w3 : (L == 2) ? w4 : (L == 3) ? w5 : w6;
  } else { base = 737280; OM = 1; O = 10; w = w7; }
  int local = idx - base;
  int j = local & 7; int t = local >> 3;
  int lanei = t & 63; t >>= 6;
  int mi = t % OM; t /= OM;
  int ks = t & 3; t >>= 2;
  int tap = t % 9; int r = t / 9;
  int n = lanei & 15, q = lanei >> 4;
  int o = mi * 16 + n;
  int ci = q * 8 + j;
  int gs = (ks - r) & 3;
  int ky = tap / 3, kx = tap % 3;
  int si, sj; rot_src(r, 3, ky, kx, si, sj);
  float val = (o < O) ? w[((o * 32 + ci) * 4 + gs) * 9 + si * 3 + sj] : 0.f;
  wrot[idx] = f2bf(val);
}

// ---------------- parallel BN finalize from bucketed partials ----------------
DINL void bn_finalize_par(const float* __restrict__ partl,
                          const float* __restrict__ gamma, const float* __restrict__ beta,
                          float* st, float* l1, float* l2, int npix, int tid) {
  if (tid < 256) {
    int c = tid & 31, grp = tid >> 5;
    float s1 = 0.f, s2 = 0.f;
    #pragma unroll
    for (int k = 0; k < 8; ++k) {
      int bk = grp * 8 + k;
      s1 += partl[bk * 128 + c];
      s2 += partl[bk * 128 + 64 + c];
    }
    l1[tid] = s1; l2[tid] = s2;
  }
  __syncthreads();
  if (tid < 32) {
    float a = 0.f, q = 0.f;
    #pragma unroll
    for (int k = 0; k < 8; ++k) { a += l1[k * 32 + tid]; q += l2[k * 32 + tid]; }
    float N = 4.f * (float)npix;
    float m = a / N;
    float v = q / N - m * m;
    float inv = rsqrtf(v + 2e-5f);
    float sc = gamma[tid] * inv;
    st[tid] = sc;
    st[32 + tid] = beta[tid] - m * sc;
  }
  __syncthreads();
}

// ---------------- layer 1 attention (standalone, parallel) ----------------
__global__ void __launch_bounds__(256)
k_att_lift(const float* __restrict__ x, const float* __restrict__ aw,
           float* __restrict__ att) {
  const int H = 48, HW = H * H;
  __shared__ float wsum[4][49];
  for (int i = threadIdx.x; i < 196; i += 256) {
    int r = i / 49; int t = i % 49;
    int ky = t / 7, kx = t % 7;
    int si, sj; rot_src(r, 7, ky, kx, si, sj);
    wsum[r][t] = aw[si * 7 + sj] + aw[49 + si * 7 + sj];
  }
  __syncthreads();
  int idx = blockIdx.x * 256 + threadIdx.x;
  if (idx >= 32 * 4 * HW) return;
  int xw = idx % H; int t = idx / H;
  int yh = t % H;  t /= H;
  int r  = t & 3;  int b = t >> 2;
  const float* xb = x + b * HW;
  float s = 0.f;
  for (int ky = 0; ky < 7; ++ky) {
    int y = yh + ky - 3;
    if ((unsigned)y >= (unsigned)H) continue;
    for (int kx = 0; kx < 7; ++kx) {
      int xx = xw + kx - 3;
      if ((unsigned)xx >= (unsigned)H) continue;
      s += xb[y * H + xx] * wsum[r][ky * 7 + kx];
    }
  }
  att[idx] = sigmoidf(s);
}

// ---------------- layer 1: LDS-tiled lifting conv + BN partial stats ----------------
__global__ void __launch_bounds__(256)
k_conv_lift(const float* __restrict__ x, const float* __restrict__ att,
            const float* __restrict__ w, const float* __restrict__ bias,
            unsigned short* __restrict__ y, float* __restrict__ partl) {
  const int HO = 46;
  __shared__ float xs[3 * 48];
  __shared__ float as[4][3 * 48];
  __shared__ float wsm[288];
  __shared__ float bs[32];
  __shared__ float bnred[64];
  int id = blockIdx.x;
  int yo = id % HO; int b = id / HO;

  for (int i = threadIdx.x; i < 144; i += 256)
    xs[i] = x[b * 2304 + (yo + i / 48) * 48 + (i % 48)];
  for (int i = threadIdx.x; i < 576; i += 256) {
    int r = i / 144; int rem = i % 144;
    as[r][rem] = att[(b * 4 + r) * 2304 + (yo + rem / 48) * 48 + (rem % 48)];
  }
  for (int i = threadIdx.x; i < 288; i += 256) wsm[i] = w[i];
  if (threadIdx.x < 32) bs[threadIdx.x] = bias[threadIdx.x];
  if (threadIdx.x < 64) bnred[threadIdx.x] = 0.f;
  __syncthreads();

  int o = threadIdx.x & 31;
  int cl = threadIdx.x >> 5;
  float wreg[9];
  #pragma unroll
  for (int i = 0; i < 9; ++i) wreg[i] = wsm[o * 9 + i];
  float bv = bs[o];
  float sacc = 0.f, qacc = 0.f;

  for (int c8 = 0; c8 < 6; ++c8) {
    int col = c8 * 8 + cl;
    if (col < HO) {
      float xv[9];
      #pragma unroll
      for (int ky = 0; ky < 3; ++ky)
        #pragma unroll
        for (int kx = 0; kx < 3; ++kx)
          xv[ky * 3 + kx] = xs[ky * 48 + col + kx];
      unsigned short* yp = y + ((size_t)b * 2116 + yo * HO + col) * 128 + o;
      #pragma unroll
      for (int r = 0; r < 4; ++r) {
        float acc = bv;
        #pragma unroll
        for (int ky = 0; ky < 3; ++ky)
          #pragma unroll
          for (int kx = 0; kx < 3; ++kx) {
            int si, sj; rot_src(r, 3, ky, kx, si, sj);  // folds: r,ky,kx constant
            acc = fmaf(as[r][ky * 48 + col + kx] * xv[ky * 3 + kx], wreg[si * 3 + sj], acc);
          }
        yp[r * 32] = f2bf(acc);
        sacc += acc; qacc += acc * acc;
      }
    }
  }
  atomicAdd(&bnred[o], sacc);
  atomicAdd(&bnred[32 + o], qacc);
  __syncthreads();
  if (threadIdx.x < 64) {
    int bucket = blockIdx.x & 63;
    int c = threadIdx.x & 31;
    int off = (threadIdx.x < 32) ? c : (64 + c);
    atomicAdd(&partl[bucket * 128 + off], bnred[threadIdx.x]);
  }
}

// ---------------- MFMA attentive GG conv (split-K staging + fused BN stats) ----------------
template<int H, int OM, int O, int OSTR, bool BNS>
__global__ void __launch_bounds__(256)
k_conv_mfma(const unsigned short* __restrict__ xn, const float* __restrict__ att,
            const unsigned short* __restrict__ wl, const float* __restrict__ bias,
            unsigned short* __restrict__ y, float* __restrict__ partl) {
  constexpr int HO = H - 2, HW = H * H;
  constexpr int TR = 8, TC = 16, WR = TR + 2, WC = TC + 2, CGH = 68;
  constexpr int NRT = (HO + TR - 1) / TR, NCT = (HO + TC - 1) / TC;
  __shared__ __align__(16) unsigned short xa[WR * WC * CGH];  // 24,480 B
  __shared__ float bnred[128];

  // XCD swizzle: blockIdx.x % 8 <-> b % 8
  int id = blockIdx.x;
  int slot = id & 7; int k = id >> 3;
  int tile = k % (NRT * NCT); k /= (NRT * NCT);
  int r = k & 3; int bhi = k >> 2;
  int b = bhi * 8 + slot;
  int rt = tile / NCT, ct = tile % NCT;
  int row0 = rt * TR, c0 = ct * TC;

  const unsigned short* xb = xn + (size_t)b * HW * 128;
  const float* ab = att + (size_t)(b * 4 + r) * HW;

  int lane = threadIdx.x & 63;
  int wv = threadIdx.x >> 6;
  int n = lane & 15, quad = lane >> 4;

  f4v acc[OM][2];
  #pragma unroll
  for (int mi = 0; mi < OM; ++mi)
    #pragma unroll
    for (int ri = 0; ri < 2; ++ri) {
      acc[mi][ri][0] = 0.f; acc[mi][ri][1] = 0.f;
      acc[mi][ri][2] = 0.f; acc[mi][ri][3] = 0.f;
    }

  const bh8* wa = (const bh8*)wl + (size_t)r * 9 * 4 * OM * 64 + lane;

  for (int half = 0; half < 2; ++half) {
    if (half) __syncthreads();  // all reads of previous half done
    // stage 64 channels: xa[pix][ch(8 chunks of 8 ushorts)]
    for (int u = threadIdx.x; u < WR * WC * 8; u += 256) {
      int ch = u & 7; int pix = u >> 3;
      int wr = pix / WC, wc = pix % WC;
      int row = row0 + wr; if (row > H - 1) row = H - 1;
      int col = c0 + wc;  if (col > H - 1) col = H - 1;
      int p = row * H + col;
      const unsigned short* xp = xb + (size_t)p * 128 + half * 64 + ch * 8;
      float av = ab[p];
      bh8 xv = *(const bh8*)xp;
      bh8 v;
      #pragma unroll
      for (int j2 = 0; j2 < 8; ++j2)
        v[j2] = (short)f2bf(bf2f((unsigned short)xv[j2]) * av);
      *(bh8*)&xa[pix * CGH + ch * 8] = v;
    }
    __syncthreads();

    #pragma unroll
    for (int tap = 0; tap < 9; ++tap) {
      int ky = tap / 3, kx = tap % 3;
      int pb0 = ((2 * wv + ky) * WC + n + kx) * CGH;
      int pb1 = pb0 + WC * CGH;
      #pragma unroll
      for (int kl = 0; kl < 2; ++kl) {
        int ks = half * 2 + kl;
        bh8 b0 = *(const bh8*)&xa[pb0 + kl * 32 + quad * 8];
        bh8 b1 = *(const bh8*)&xa[pb1 + kl * 32 + quad * 8];
        bh8 a0 = wa[(size_t)((tap * 4 + ks) * OM + 0) * 64];
        acc[0][0] = __builtin_amdgcn_mfma_f32_16x16x32_bf16(a0, b0, acc[0][0], 0, 0, 0);
        acc[0][1] = __builtin_amdgcn_mfma_f32_16x16x32_bf16(a0, b1, acc[0][1], 0, 0, 0);
        if constexpr (OM == 2) {
          bh8 a1 = wa[(size_t)((tap * 4 + ks) * OM + 1) * 64];
          acc[1][0] = __builtin_amdgcn_mfma_f32_16x16x32_bf16(a1, b0, acc[1][0], 0, 0, 0);
          acc[1][1] = __builtin_amdgcn_mfma_f32_16x16x32_bf16(a1, b1, acc[1][1], 0, 0, 0);
        }
      }
    }
  }

  // epilogue: C/D col=lane&15 (spatial), row=quad*4+reg (o); c' = r*O + o
  float sv[OM * 4], qv[OM * 4];
  #pragma unroll
  for (int e = 0; e < OM * 4; ++e) { sv[e] = 0.f; qv[e] = 0.f; }
  #pragma unroll
  for (int mi = 0; mi < OM; ++mi)
    #pragma unroll
    for (int ri = 0; ri < 2; ++ri) {
      int prow = row0 + 2 * wv + ri;
      int col = c0 + n;
      if (prow < HO && col < HO) {
        unsigned short* yp = y + ((size_t)b * HO * HO + prow * HO + col) * OSTR;
        int o0 = mi * 16 + quad * 4;
        f4v v = acc[mi][ri];
        if constexpr (O == 32) {
          us4 w4;
          #pragma unroll
          for (int reg = 0; reg < 4; ++reg) {
            float val = v[reg] + bias[o0 + reg];
            w4[reg] = f2bf(val);
            if constexpr (BNS) { sv[mi * 4 + reg] += val; qv[mi * 4 + reg] += val * val; }
          }
          *(us4*)(yp + r * 32 + o0) = w4;
        } else {
          #pragma unroll
          for (int reg = 0; reg < 4; ++reg) {
            int o = o0 + reg;
            if (o < O) yp[r * O + o] = f2bf(v[reg] + bias[o]);
          }
        }
      }
    }

  if constexpr (BNS) {
    #pragma unroll
    for (int e = 0; e < OM * 4; ++e) {
      #pragma unroll
      for (int off = 1; off < 16; off <<= 1) {
        sv[e] += __shfl_xor(sv[e], off);
        qv[e] += __shfl_xor(qv[e], off);
      }
    }
    if (threadIdx.x < 128) bnred[threadIdx.x] = 0.f;
    __syncthreads();
    if (n == 0) {
      #pragma unroll
      for (int e = 0; e < OM * 4; ++e) {
        int o = (e >> 2) * 16 + quad * 4 + (e & 3);
        atomicAdd(&bnred[o], sv[e]);
        atomicAdd(&bnred[64 + o], qv[e]);
      }
    }
    __syncthreads();
    if (threadIdx.x < 128)
      atomicAdd(&partl[(blockIdx.x & 63) * 128 + threadIdx.x], bnred[threadIdx.x]);
  }
}

// ---------------- L1: fused BN-finalize+BN+ReLU+mean/max (standalone) ----------------
__global__ void __launch_bounds__(256)
k_meanmax_bn(const unsigned short* __restrict__ yr, const float* __restrict__ partl,
             const float* __restrict__ gamma, const float* __restrict__ beta,
             unsigned short* __restrict__ xn, unsigned short* __restrict__ amap,
             int npix) {
  __shared__ float st[64];
  __shared__ float l1[256], l2[256];
  bn_finalize_par(partl, gamma, beta, st, l1, l2, npix, threadIdx.x);
  int idx = blockIdx.x * 256 + threadIdx.x;
  if (idx >= npix) return;
  const unsigned short* yp = yr + (size_t)idx * 128;
  unsigned short* xp = xn + (size_t)idx * 128;
  float sm[4] = {0.f, 0.f, 0.f, 0.f};
  float mx[4] = {-1e30f, -1e30f, -1e30f, -1e30f};
  #pragma unroll 4
  for (int oo = 0; oo < 16; ++oo) {
    int g = oo >> 2, ob = (oo & 3) * 8;
    bh8 raw = *(const bh8*)(yp + oo * 8);
    bh8 w;
    #pragma unroll
    for (int e = 0; e < 8; ++e) {
      float v = fmaxf(fmaf(bf2f((unsigned short)raw[e]), st[ob + e], st[32 + ob + e]), 0.f);
      w[e] = (short)f2bf(v);
      sm[g] += v;
      mx[g] = fmaxf(mx[g], v);
    }
    *(bh8*)(xp + oo * 8) = w;
  }
  bh8 am;
  #pragma unroll
  for (int g = 0; g < 4; ++g) {
    am[g] = (short)f2bf(sm[g] * (1.f / 32.f));
    am[4 + g] = (short)f2bf(mx[g]);
  }
  *(bh8*)(amap + (size_t)idx * 8) = am;
}

// ---------------- L1 attention GG conv (LDS-staged rotated weights) ----------------
__global__ void __launch_bounds__(256)
k_att_gg(const unsigned short* __restrict__ amap, const float* __restrict__ aw,
         float* __restrict__ att, int h) {
  __shared__ float wsa[4][4][49], wsx[4][4][49];
  for (int i = threadIdx.x; i < 784; i += 256) {
    int r = i / 196; int rem = i % 196;
    int g = rem / 49; int t = rem % 49;
    int ky = t / 7, kx = t % 7;
    int si, sj; rot_src(r, 7, ky, kx, si, sj);
    int gs = (g - r) & 3;
    wsa[r][g][t] = aw[gs * 49 + si * 7 + sj];
    wsx[r][g][t] = aw[(4 + gs) * 49 + si * 7 + sj];
  }
  __syncthreads();
  int hw = h * h;
  int idx = blockIdx.x * 256 + threadIdx.x;
  if (idx >= 32 * 4 * hw) return;
  int p = idx % hw; int t = idx / hw;
  int r = t & 3; int b = t >> 2;
  int yh = p / h, xw = p % h;
  float s = 0.f;
  for (int ky = 0; ky < 7; ++ky) {
    int y = yh + ky - 3;
    if ((unsigned)y >= (unsigned)h) continue;
    for (int kx = 0; kx < 7; ++kx) {
      int xx = xw + kx - 3;
      if ((unsigned)xx >= (unsigned)h) continue;
      int tp = ky * 7 + kx;
      bh8 av = *(const bh8*)(amap + ((size_t)b * hw + y * h + xx) * 8);
      #pragma unroll
      for (int g = 0; g < 4; ++g)
        s += bf2f((unsigned short)av[g]) * wsa[r][g][tp]
           + bf2f((unsigned short)av[4 + g]) * wsx[r][g][tp];
    }
  }
  att[idx] = sigmoidf(s);
}

// ---------------- fused post-layer (L2..L6), row-group parallel ----------------
// grid = 32 b x 4 row-groups; block 256. Each block computes amap for its owned
// rows + 3-row halo into LDS (recompute, reads L2-cached), writes xn for owned
// rows only, then attention conv for owned 4r x RG x HOUT outputs.
template<int HIN, int HOUT, bool POOL>
__global__ void __launch_bounds__(256)
k_post(const unsigned short* __restrict__ yr, const float* __restrict__ partl,
       const float* __restrict__ gamma, const float* __restrict__ beta,
       const float* __restrict__ aw,
       unsigned short* __restrict__ xn, float* __restrict__ att) {
  constexpr int RG = (HOUT + 3) / 4;           // owned rows per block
  constexpr int AR = RG + 6;                   // staged amap rows (halo 3+3)
  __shared__ __align__(16) unsigned short amap_l[AR * HOUT * 8];
  __shared__ float wsa[4][4][49], wsx[4][4][49];
  __shared__ float st[64];
  __shared__ float l1[256], l2[256];
  int tid = threadIdx.x;
  int b = blockIdx.x >> 2;
  int rg = blockIdx.x & 3;
  int row0 = rg * RG;
  int row1 = row0 + RG; if (row1 > HOUT) row1 = HOUT;
  int lo = row0 - 3; if (lo < 0) lo = 0;
  int hi = row0 + RG + 3; if (hi > HOUT) hi = HOUT;
  int base = row0 - 3;                         // LDS row index = row - base

  for (int i = tid; i < 784; i += 256) {
    int r = i / 196; int rem = i % 196;
    int g = rem / 49; int t = rem % 49;
    int ky = t / 7, kx = t % 7;
    int si, sj; rot_src(r, 7, ky, kx, si, sj);
    int gs = (g - r) & 3;
    wsa[r][g][t] = aw[gs * 49 + si * 7 + sj];
    wsx[r][g][t] = aw[(4 + gs) * 49 + si * 7 + sj];
  }
  bn_finalize_par(partl, gamma, beta, st, l1, l2, 32 * HIN * HIN, tid);

  // phase 1: BN+ReLU (+pool) for rows [lo, hi); xn write for owned rows only
  int npx = (hi - lo) * HOUT;
  for (int i = tid; i < npx; i += 256) {
    int row = lo + i / HOUT, col = i % HOUT;
    int p = row * HOUT + col;
    bool owned = (row >= row0 && row < row1);
    float sm[4] = {0.f, 0.f, 0.f, 0.f};
    float mx[4] = {-1e30f, -1e30f, -1e30f, -1e30f};
    unsigned short* xp = xn + ((size_t)b * HOUT * HOUT + p) * 128;
    if constexpr (POOL) {
      int y0 = row * 2, x0 = col * 2;
      const unsigned short* p00 = yr + ((size_t)b * HIN * HIN + y0 * HIN + x0) * 128;
      #pragma unroll 2
      for (int oo = 0; oo < 16; ++oo) {
        int g = oo >> 2, ob = (oo & 3) * 8;
        bh8 r0 = *(const bh8*)(p00 + oo * 8);
        bh8 r1 = *(const bh8*)(p00 + 128 + oo * 8);
        bh8 r2 = *(const bh8*)(p00 + (size_t)HIN * 128 + oo * 8);
        bh8 r3 = *(const bh8*)(p00 + (size_t)(HIN + 1) * 128 + oo * 8);
        bh8 w;
        #pragma unroll
        for (int e = 0; e < 8; ++e) {
          float sc = st[ob + e], sh = st[32 + ob + e];
          float a0 = fmaxf(fmaf(bf2f((unsigned short)r0[e]), sc, sh), 0.f);
          float a1 = fmaxf(fmaf(bf2f((unsigned short)r1[e]), sc, sh), 0.f);
          float a2 = fmaxf(fmaf(bf2f((unsigned short)r2[e]), sc, sh), 0.f);
          float a3 = fmaxf(fmaf(bf2f((unsigned short)r3[e]), sc, sh), 0.f);
          float val = fmaxf(fmaxf(a0, a1), fmaxf(a2, a3));
          w[e] = (short)f2bf(val);
          sm[g] += val; mx[g] = fmaxf(mx[g], val);
        }
        if (owned) *(bh8*)(xp + oo * 8) = w;
      }
    } else {
      const unsigned short* yp = yr + ((size_t)b * HOUT * HOUT + p) * 128;
      #pragma unroll 4
      for (int oo = 0; oo < 16; ++oo) {
        int g = oo >> 2, ob = (oo & 3) * 8;
        bh8 raw = *(const bh8*)(yp + oo * 8);
        bh8 w;
        #pragma unroll
        for (int e = 0; e < 8; ++e) {
          float v = fmaxf(fmaf(bf2f((unsigned short)raw[e]), st[ob + e], st[32 + ob + e]), 0.f);
          w[e] = (short)f2bf(v);
          sm[g] += v;
          mx[g] = fmaxf(mx[g], v);
        }
        if (owned) *(bh8*)(xp + oo * 8) = w;
      }
    }
    bh8 am;
    #pragma unroll
    for (int g = 0; g < 4; ++g) {
      am[g] = (short)f2bf(sm[g] * (1.f / 32.f));
      am[4 + g] = (short)f2bf(mx[g]);
    }
    *(bh8*)&amap_l[((row - base) * HOUT + col) * 8] = am;
  }
  __syncthreads();

  // phase 2: attention conv for owned rows from LDS amap
  int nout = 4 * (row1 - row0) * HOUT;
  for (int i = tid; i < nout; i += 256) {
    int r = i / ((row1 - row0) * HOUT);
    int rem = i % ((row1 - row0) * HOUT);
    int yh = row0 + rem / HOUT, xw = rem % HOUT;
    float s = 0.f;
    for (int ky = 0; ky < 7; ++ky) {
      int y = yh + ky - 3;
      if ((unsigned)y >= (unsigned)HOUT) continue;
      for (int kx = 0; kx < 7; ++kx) {
        int xx = xw + kx - 3;
        if ((unsigned)xx >= (unsigned)HOUT) continue;
        int tp = ky * 7 + kx;
        bh8 av = *(const bh8*)&amap_l[((y - base) * HOUT + xx) * 8];
        #pragma unroll
        for (int g = 0; g < 4; ++g)
          s += bf2f((unsigned short)av[g]) * wsa[r][g][tp]
             + bf2f((unsigned short)av[4 + g]) * wsx[r][g][tp];
      }
    }
    att[((size_t)(b * 4 + r)) * HOUT * HOUT + yh * HOUT + xw] = sigmoidf(s);
  }
}

// ---------------- final: rotation max + spatial mean ----------------
__global__ void k_final(const unsigned short* __restrict__ y7, float* __restrict__ out) {
  int idx = blockIdx.x * blockDim.x + threadIdx.x;
  if (idx >= 320) return;
  int o = idx % 10; int b = idx / 10;
  const unsigned short* p = y7 + (size_t)b * 144 * 40;
  float s = 0.f;
  for (int sp = 0; sp < 144; ++sp) {
    const unsigned short* q = p + sp * 40 + o;
    float m = fmaxf(fmaxf(bf2f(q[0]), bf2f(q[10])), fmaxf(bf2f(q[20]), bf2f(q[30])));
    s += m;
  }
  out[idx] = s * (1.f / 144.f);
}

// ---------------- host ----------------

extern "C" void kernel_launch(void* const* d_in, const int* in_sizes, int n_in,
                              void* d_out, int out_size, void* d_ws, size_t ws_size,
                              hipStream_t stream) {
  (void)in_sizes; (void)n_in; (void)out_size; (void)ws_size;
  const float* x   = (const float*)d_in[0];
  const float* w1  = (const float*)d_in[1];
  const float* b1  = (const float*)d_in[2];
  const float* aw1 = (const float*)d_in[3];
  const float* W[6];  const float* BI[6]; const float* AW[6];
  for (int i = 0; i < 6; ++i) {
    W[i]  = (const float*)d_in[4 + 3 * i];
    BI[i] = (const float*)d_in[5 + 3 * i];
    AW[i] = (const float*)d_in[6 + 3 * i];
  }
  const float* G[6]; const float* BE[6];
  for (int i = 0; i < 6; ++i) {
    G[i]  = (const float*)d_in[22 + 2 * i];
    BE[i] = (const float*)d_in[23 + 2 * i];
  }
  float* out = (float*)d_out;

  // workspace (floats): ~38.8 MB
  float* ws = (float*)d_ws;
  unsigned short* YR = (unsigned short*)ws;                  // raw conv out bf16
  unsigned short* XN = (unsigned short*)(ws + 4333568);      // normalized xn bf16
  unsigned short* AMAP = (unsigned short*)(ws + 8667136);    // L1 amap, 541,696 ush
  float* ATT = ws + 8937984;                                 // 294,912
  unsigned short* WROT = (unsigned short*)(ws + 9232896);    // 811,008 ush
  float* PART  = ws + 9638400;                               // 6 layers x 8192

  auto cdiv = [](int a, int b) { return (a + b - 1) / b; };
  float* PL[6];
  for (int i = 0; i < 6; ++i) PL[i] = PART + i * 8192;

  // zero the BN stat buckets (re-poisoned to 0xAA before every timed launch)
  hipMemsetAsync(PART, 0, 6 * 8192 * sizeof(float), stream);

  // weight prep (all 6 GG layers, one launch)
  k_prep_w<<<dim3(cdiv(811008, 256)), dim3(256), 0, stream>>>(
      W[0], W[1], W[2], W[3], W[4], W[5], WROT);
  const unsigned short* WL[6];
  for (int i = 0; i < 5; ++i) WL[i] = WROT + i * 147456;
  WL[5] = WROT + 737280;

  // ---- layer 1: attention + lifting conv (stats fused) + meanmax + att ----
  {
    int natt = 32 * 4 * 48 * 48;
    k_att_lift<<<dim3(cdiv(natt, 256)), dim3(256), 0, stream>>>(x, aw1, ATT);
    k_conv_lift<<<dim3(32 * 46), dim3(256), 0, stream>>>(x, ATT, w1, b1, YR, PL[0]);
    int npix = 32 * 2116;
    k_meanmax_bn<<<dim3(cdiv(npix, 256)), dim3(256), 0, stream>>>(YR, PL[0], G[0], BE[0], XN, AMAP, npix);
    k_att_gg<<<dim3(cdiv(npix * 4, 256)), dim3(256), 0, stream>>>(AMAP, AW[0], ATT, 46);
  }
  // ---- layer 2 (H=46 -> 44) + fused pool/post ----
  k_conv_mfma<46, 2, 32, 128, true><<<dim3(128 * 6 * 3), dim3(256), 0, stream>>>(XN, ATT, WL[0], BI[0], YR, PL[1]);
  k_post<44, 22, true><<<dim3(128), dim3(256), 0, stream>>>(YR, PL[1], G[1], BE[1], AW[1], XN, ATT);
  // ---- layer 3 (22 -> 20) ----
  k_conv_mfma<22, 2, 32, 128, true><<<dim3(128 * 3 * 2), dim3(256), 0, stream>>>(XN, ATT, WL[1], BI[1], YR, PL[2]);
  k_post<20, 20, false><<<dim3(128), dim3(256), 0, stream>>>(YR, PL[2], G[2], BE[2], AW[2], XN, ATT);
  // ---- layer 4 (20 -> 18) ----
  k_conv_mfma<20, 2, 32, 128, true><<<dim3(128 * 3 * 2), dim3(256), 0, stream>>>(XN, ATT, WL[2], BI[2], YR, PL[3]);
  k_post<18, 18, false><<<dim3(128), dim3(256), 0, stream>>>(YR, PL[3], G[3], BE[3], AW[3], XN, ATT);
  // ---- layer 5 (18 -> 16) ----
  k_conv_mfma<18, 2, 32, 128, true><<<dim3(128 * 2 * 1), dim3(256), 0, stream>>>(XN, ATT, WL[3], BI[3], YR, PL[4]);
  k_post<16, 16, false><<<dim3(128), dim3(256), 0, stream>>>(YR, PL[4], G[4], BE[4], AW[4], XN, ATT);
  // ---- layer 6 (16 -> 14) ----
  k_conv_mfma<16, 2, 32, 128, true><<<dim3(128 * 2 * 1), dim3(256), 0, stream>>>(XN, ATT, WL[4], BI[4], YR, PL[5]);
  k_post<14, 14, false><<<dim3(128), dim3(256), 0, stream>>>(YR, PL[5], G[5], BE[5], AW[5], XN, ATT);
  // ---- layer 7 (14 -> 12, O=10, no BN) ----
  k_conv_mfma<14, 1, 10, 40, false><<<dim3(128 * 2 * 1), dim3(256), 0, stream>>>(XN, ATT, WL[5], BI[5], YR, nullptr);
  // ---- rotation max + spatial mean ----
  k_final<<<dim3(5), dim3(64), 0, stream>>>(YR, out);
}